// Round 2
// baseline (1035.691 us; speedup 1.0000x reference)
//
#include <hip/hip_runtime.h>

// Problem constants (match reference setup_inputs)
#define NB    50000   // nodes
#define BB    64      // batch  (== wavefront size: lane = b)
#define DD    16      // neighbors per node
#define NDRVN 1000    // driver nodes

// ---------------------------------------------------------------------------
// Force a (uniform) value into a VGPR.  Measured in a prior session: v_fma
// with an SGPR broadcast operand issues at ~half the all-VGPR rate on gfx950,
// so weights must be moved to VGPRs (one v_mov each) before the FMA chains.
__device__ __forceinline__ float vg(float s) {
    asm("" : "+v"(s));
    return s;
}

// ---------------------------------------------------------------------------
// Transpose x (B,N) -> z0 (N,B).
__global__ __launch_bounds__(256) void transpose_kernel(
    const float* __restrict__ x, float* __restrict__ xT)
{
    int tid = blockIdx.x * 256 + threadIdx.x;   // tid = n*64 + b
    int n = tid >> 6;
    int b = tid & 63;
    if (n < NB) xT[tid] = x[b * NB + n];
}

// ---------------------------------------------------------------------------
// One 5->5 conv1x3+relu layer, ONE node per wave, scalar v_fma_f32.
// x-outer / channel-inner: in-columns die as out-columns are produced, so
// data liveness stays ~5*WIN floats + 80 weight/bias VGPRs.
template<int WIN>
__device__ __forceinline__ void conv5(const float (&in)[5][14], float (&out)[5][14],
                                      const float* __restrict__ w,
                                      const float* __restrict__ b)
{
    constexpr int WOUT = WIN - 2;
    float wr[75];
#pragma unroll
    for (int t = 0; t < 75; ++t) wr[t] = vg(w[t]);
    float bb[5];
#pragma unroll
    for (int c = 0; c < 5; ++c) bb[c] = vg(b[c]);

#pragma unroll
    for (int x = 0; x < WOUT; ++x) {
#pragma unroll
        for (int c = 0; c < 5; ++c) {
            // bias folded into the first fma's addend: no acc-init mov
            float acc = fmaf(wr[c * 15 + 0], in[0][x + 0], bb[c]);
            acc = fmaf(wr[c * 15 + 1], in[0][x + 1], acc);
            acc = fmaf(wr[c * 15 + 2], in[0][x + 2], acc);
#pragma unroll
            for (int ci = 1; ci < 5; ++ci) {
                acc = fmaf(wr[c * 15 + ci * 3 + 0], in[ci][x + 0], acc);
                acc = fmaf(wr[c * 15 + ci * 3 + 1], in[ci][x + 1], acc);
                acc = fmaf(wr[c * 15 + ci * 3 + 2], in[ci][x + 2], acc);
            }
            out[c][x] = fmaxf(acc, 0.0f);
        }
    }
}

// ---------------------------------------------------------------------------
// One full pass, ONE node per wave, scalar f32 FMA chains.
// waves_per_eu(2,2): 256-VGPR budget so the ~230-reg peak liveness
// (70 in + 60 out + 80 weights + misc) fits with zero spills.
__global__ __launch_bounds__(256)
__attribute__((amdgpu_waves_per_eu(2, 2)))
void pass_kernel(
    const float* __restrict__ zin, float* __restrict__ zout,
    const int*  __restrict__ nidx,
    const float* __restrict__ w0, const float* __restrict__ b0,
    const float* __restrict__ w1, const float* __restrict__ b1,
    const float* __restrict__ w2, const float* __restrict__ b2,
    const float* __restrict__ w3, const float* __restrict__ b3,
    const float* __restrict__ w4, const float* __restrict__ b4,
    const float* __restrict__ w5, const float* __restrict__ b5,
    const float* __restrict__ w6, const float* __restrict__ b6)
{
    int lane = threadIdx.x & 63;
    int wv   = blockIdx.x * 4 + (threadIdx.x >> 6);   // 50000 waves, 1 node each
    int n    = __builtin_amdgcn_readfirstlane(wv);

    // Neighbor indices: 16 contiguous ints, uniform -> s_load_dwordx16.
    const int* ip = nidx + n * DD;

    // Gather this node's neighborhood (rows of 256B, perfectly coalesced).
    float g[16];
#pragma unroll
    for (int d = 0; d < 16; ++d)
        g[d] = zin[(size_t)ip[d] * BB + lane];

    float ha[5][14], hb[5][14];

    // Layer 0: 1 -> 5 channels, width 16 -> 14
    {
        float wr[15], bb[5];
#pragma unroll
        for (int t = 0; t < 15; ++t) wr[t] = vg(w0[t]);
#pragma unroll
        for (int c = 0; c < 5; ++c) bb[c] = vg(b0[c]);
#pragma unroll
        for (int x = 0; x < 14; ++x) {
#pragma unroll
            for (int c = 0; c < 5; ++c) {
                float acc = fmaf(wr[c * 3 + 0], g[x + 0], bb[c]);
                acc = fmaf(wr[c * 3 + 1], g[x + 1], acc);
                acc = fmaf(wr[c * 3 + 2], g[x + 2], acc);
                ha[c][x] = fmaxf(acc, 0.0f);
            }
        }
    }

    conv5<14>(ha, hb, w1, b1);   // 14 -> 12
    conv5<12>(hb, ha, w2, b2);   // 12 -> 10
    conv5<10>(ha, hb, w3, b3);   // 10 -> 8
    conv5<8> (hb, ha, w4, b4);   // 8  -> 6
    conv5<6> (ha, hb, w5, b5);   // 6  -> 4

    // Layer 6: 5 -> 1, width 4 -> 2, then pair-average.
    {
        float wr[15];
#pragma unroll
        for (int t = 0; t < 15; ++t) wr[t] = vg(w6[t]);
        float bias = vg(b6[0]);

        float t0 = fmaf(wr[0], hb[0][0], bias);
        float t1 = fmaf(wr[0], hb[0][1], bias);
        t0 = fmaf(wr[1], hb[0][1], t0);
        t0 = fmaf(wr[2], hb[0][2], t0);
        t1 = fmaf(wr[1], hb[0][2], t1);
        t1 = fmaf(wr[2], hb[0][3], t1);
#pragma unroll
        for (int ci = 1; ci < 5; ++ci) {
#pragma unroll
            for (int t = 0; t < 3; ++t) {
                t0 = fmaf(wr[ci * 3 + t], hb[ci][0 + t], t0);
                t1 = fmaf(wr[ci * 3 + t], hb[ci][1 + t], t1);
            }
        }
        t0 = fmaxf(t0, 0.0f);
        t1 = fmaxf(t1, 0.0f);
        zout[(size_t)n * BB + lane] = 0.5f * (t0 + t1);
    }
}

// ---------------------------------------------------------------------------
// Final driver gather: out[b, i] = z[driver_idx[i], b]   (out is (B, NDRV))
__global__ __launch_bounds__(256) void gather_out_kernel(
    const float* __restrict__ z, const int* __restrict__ didx,
    float* __restrict__ out)
{
    int i = blockIdx.x * 256 + threadIdx.x;
    if (i >= BB * NDRVN) return;
    int b = i / NDRVN;
    int k = i - b * NDRVN;
    out[i] = z[(size_t)didx[k] * BB + b];
}

// ---------------------------------------------------------------------------
extern "C" void kernel_launch(void* const* d_in, const int* in_sizes, int n_in,
                              void* d_out, int out_size, void* d_ws, size_t ws_size,
                              hipStream_t stream)
{
    const float* x    = (const float*)d_in[0];
    const int*   nidx = (const int*)  d_in[1];
    const int*   didx = (const int*)  d_in[2];
    const float* w[7];
    const float* b[7];
    for (int i = 0; i < 7; ++i) {
        w[i] = (const float*)d_in[3 + 2 * i];
        b[i] = (const float*)d_in[4 + 2 * i];
    }

    // Workspace: two ping-pong z buffers in (N, B) layout, 12.8 MB each.
    float* z0 = (float*)d_ws;
    float* z1 = z0 + (size_t)NB * BB;

    const int tblocks = (NB * BB) / 256;   // 12500 (transpose)
    const int pblocks = NB / 4;            // 12500: 4 waves x 1 node

    transpose_kernel<<<tblocks, 256, 0, stream>>>(x, z0);

    pass_kernel<<<pblocks, 256, 0, stream>>>(z0, z1, nidx,
        w[0], b[0], w[1], b[1], w[2], b[2], w[3], b[3],
        w[4], b[4], w[5], b[5], w[6], b[6]);
    pass_kernel<<<pblocks, 256, 0, stream>>>(z1, z0, nidx,
        w[0], b[0], w[1], b[1], w[2], b[2], w[3], b[3],
        w[4], b[4], w[5], b[5], w[6], b[6]);
    pass_kernel<<<pblocks, 256, 0, stream>>>(z0, z1, nidx,
        w[0], b[0], w[1], b[1], w[2], b[2], w[3], b[3],
        w[4], b[4], w[5], b[5], w[6], b[6]);
    pass_kernel<<<pblocks, 256, 0, stream>>>(z1, z0, nidx,
        w[0], b[0], w[1], b[1], w[2], b[2], w[3], b[3],
        w[4], b[4], w[5], b[5], w[6], b[6]);

    gather_out_kernel<<<(BB * NDRVN + 255) / 256, 256, 0, stream>>>(z0, didx, (float*)d_out);
}

// Round 3
// 961.164 us; speedup vs baseline: 1.0775x; 1.0775x over previous
//
#include <hip/hip_runtime.h>

// Problem constants (match reference setup_inputs)
#define NB    50000   // nodes
#define BB    64      // batch  (== wavefront size: lane = b)
#define DD    16      // neighbors per node
#define NDRVN 1000    // driver nodes

typedef float f2 __attribute__((ext_vector_type(2)));

// ---------------------------------------------------------------------------
// Force a (uniform) value into a VGPR (one v_mov from SGPR).
__device__ __forceinline__ float vg(float s) {
    asm("" : "+v"(s));
    return s;
}
// Pack two uniform floats (from s_loads) into one f2 VGPR pair: 2 v_movs.
__device__ __forceinline__ f2 pack2(float lo, float hi) {
    f2 r;
    r.x = vg(lo);
    r.y = vg(hi);
    return r;
}

// relu on a packed pair -> v_pk_max_f32
__device__ __forceinline__ f2 relu2(f2 a) {
    return __builtin_elementwise_max(a, (f2)0.0f);
}

// ---------------------------------------------------------------------------
// VOP3P op_sel broadcast FMAs (HW-verified in round 1: absmax matched).
// Weights stay packed 2-per-64b-register; op_sel/op_sel_hi pick one half of
// the weight pair (and of the bias pair for the first tap) and broadcast it
// to both halves of the result.  Weight cost: 1 VGPR/weight, no splat pairs.
//
// acc += w.lo * in
__device__ __forceinline__ void fma_wlo(f2 w, f2 in, f2& acc) {
    asm("v_pk_fma_f32 %0, %1, %2, %0 op_sel_hi:[0,1,1]"
        : "+v"(acc) : "v"(w), "v"(in));
}
// acc += w.hi * in
__device__ __forceinline__ void fma_whi(f2 w, f2 in, f2& acc) {
    asm("v_pk_fma_f32 %0, %1, %2, %0 op_sel:[1,0,0] op_sel_hi:[1,1,1]"
        : "+v"(acc) : "v"(w), "v"(in));
}
// d = w.lo * in + b.lo
__device__ __forceinline__ f2 fma_wb_ll(f2 w, f2 in, f2 b) {
    f2 d;
    asm("v_pk_fma_f32 %0, %1, %2, %3 op_sel_hi:[0,1,0]"
        : "=v"(d) : "v"(w), "v"(in), "v"(b));
    return d;
}
// d = w.lo * in + b.hi
__device__ __forceinline__ f2 fma_wb_lh(f2 w, f2 in, f2 b) {
    f2 d;
    asm("v_pk_fma_f32 %0, %1, %2, %3 op_sel:[0,0,1] op_sel_hi:[0,1,1]"
        : "=v"(d) : "v"(w), "v"(in), "v"(b));
    return d;
}
// d = w.hi * in + b.lo
__device__ __forceinline__ f2 fma_wb_hl(f2 w, f2 in, f2 b) {
    f2 d;
    asm("v_pk_fma_f32 %0, %1, %2, %3 op_sel:[1,0,0] op_sel_hi:[1,1,0]"
        : "=v"(d) : "v"(w), "v"(in), "v"(b));
    return d;
}
// d = w.hi * in + b.hi
__device__ __forceinline__ f2 fma_wb_hh(f2 w, f2 in, f2 b) {
    f2 d;
    asm("v_pk_fma_f32 %0, %1, %2, %3 op_sel:[1,0,1] op_sel_hi:[1,1,1]"
        : "=v"(d) : "v"(w), "v"(in), "v"(b));
    return d;
}

// j is a compile-time constant after full unrolling -> branch folds away.
__device__ __forceinline__ void conv_step(const f2* wp, int j, f2 in, f2& acc) {
    if (j & 1) fma_whi(wp[j >> 1], in, acc);
    else       fma_wlo(wp[j >> 1], in, acc);
}
// first tap: fold the bias into src2 via op_sel (no bias splat, no init mov)
__device__ __forceinline__ f2 conv_begin(const f2* wp, int jw, const f2* bp,
                                         int jb, f2 in) {
    f2 w = wp[jw >> 1], b = bp[jb >> 1];
    if (jw & 1) return (jb & 1) ? fma_wb_hh(w, in, b) : fma_wb_hl(w, in, b);
    else        return (jb & 1) ? fma_wb_lh(w, in, b) : fma_wb_ll(w, in, b);
}

// ---------------------------------------------------------------------------
// Weight staging: uniform derefs -> s_load batches (scalar L1 hot after the
// first wave), then explicit v_mov pairs into VGPR f2 packs.  This replaces
// round 1's vector-load path whose 7 dependent global-load batches per node
// stalled at low occupancy.
__device__ __forceinline__ void load_w75(const float* __restrict__ w,
                                         const float* __restrict__ b,
                                         f2 (&wp)[38], f2 (&bp)[3]) {
#pragma unroll
    for (int i = 0; i < 37; ++i) wp[i] = pack2(w[2 * i], w[2 * i + 1]);
    wp[37] = pack2(w[74], 0.0f);
    bp[0] = pack2(b[0], b[1]);
    bp[1] = pack2(b[2], b[3]);
    bp[2] = pack2(b[4], 0.0f);
}

__device__ __forceinline__ void load_w15(const float* __restrict__ w,
                                         const float* __restrict__ b, int nb,
                                         f2 (&wp)[8], f2 (&bp)[3]) {
#pragma unroll
    for (int i = 0; i < 7; ++i) wp[i] = pack2(w[2 * i], w[2 * i + 1]);
    wp[7] = pack2(w[14], 0.0f);
    if (nb == 5) {
        bp[0] = pack2(b[0], b[1]);
        bp[1] = pack2(b[2], b[3]);
        bp[2] = pack2(b[4], 0.0f);
    } else {
        bp[0] = pack2(b[0], 0.0f);
        bp[1] = (f2)0.0f;
        bp[2] = (f2)0.0f;
    }
}

// ---------------------------------------------------------------------------
// Transpose x (B,N) -> z0 (N,B).
__global__ __launch_bounds__(256) void transpose_kernel(
    const float* __restrict__ x, float* __restrict__ xT)
{
    int tid = blockIdx.x * 256 + threadIdx.x;   // tid = n*64 + b
    int n = tid >> 6;
    int b = tid & 63;
    if (n < NB) xT[tid] = x[b * NB + n];
}

// ---------------------------------------------------------------------------
// One 5->5 conv1x3+relu layer for TWO nodes packed as f2 (.x=node A, .y=B).
// x-outer / channel-inner: in-columns die as out-columns are produced.
template<int WIN>
__device__ __forceinline__ void conv5p(const f2 (&in)[5][14], f2 (&out)[5][14],
                                       const f2 (&wp)[38], const f2 (&bp)[3])
{
    constexpr int WOUT = WIN - 2;
#pragma unroll
    for (int x = 0; x < WOUT; ++x) {
#pragma unroll
        for (int c = 0; c < 5; ++c) {
            const int j0 = c * 15;      // parity folds at compile time
            f2 acc = conv_begin(wp, j0, bp, c, in[0][x]);
            conv_step(wp, j0 + 1, in[0][x + 1], acc);
            conv_step(wp, j0 + 2, in[0][x + 2], acc);
#pragma unroll
            for (int ci = 1; ci < 5; ++ci) {
#pragma unroll
                for (int t = 0; t < 3; ++t)
                    conv_step(wp, j0 + ci * 3 + t, in[ci][x + t], acc);
            }
            out[c][x] = relu2(acc);
        }
    }
}

// ---------------------------------------------------------------------------
// One full pass, TWO nodes per wave packed into f2 lanes.
// waves_per_eu(2,8): 256-VGPR budget (round 1 proved natural liveness is
// ~124 regs, no spills) while letting HW run up to 4 waves/SIMD for latency
// hiding -- round 1/2's (2,2) cap was a self-inflicted stall.
__global__ __launch_bounds__(256)
__attribute__((amdgpu_waves_per_eu(2, 8)))
void pass_kernel(
    const float* __restrict__ zin, float* __restrict__ zout,
    const int*  __restrict__ nidx,
    const float* __restrict__ w0, const float* __restrict__ b0,
    const float* __restrict__ w1, const float* __restrict__ b1,
    const float* __restrict__ w2, const float* __restrict__ b2,
    const float* __restrict__ w3, const float* __restrict__ b3,
    const float* __restrict__ w4, const float* __restrict__ b4,
    const float* __restrict__ w5, const float* __restrict__ b5,
    const float* __restrict__ w6, const float* __restrict__ b6)
{
    int lane   = threadIdx.x & 63;
    int waveid = blockIdx.x * 4 + (threadIdx.x >> 6);     // 25000 waves
    int n0 = __builtin_amdgcn_readfirstlane(waveid * 2);  // nodes n0, n0+1

    // Neighbor indices for both nodes: 32 contiguous ints -> s_loads.
    const int* ip = nidx + n0 * DD;

    // Gather both nodes' neighborhoods into f2 pairs (.x = A, .y = B).
    f2 g[16];
#pragma unroll
    for (int d = 0; d < 16; ++d) {
        float a = zin[(size_t)ip[d]      * BB + lane];
        float b = zin[(size_t)ip[16 + d] * BB + lane];
        g[d] = (f2){a, b};
    }

    f2 ha[5][14], hb[5][14];

    // Layer 0: 1 -> 5 channels, width 16 -> 14
    // (weight staging s_loads/movs overlap the gather's vmcnt wait)
    {
        f2 wp[8], bp[3];
        load_w15(w0, b0, 5, wp, bp);
#pragma unroll
        for (int x = 0; x < 14; ++x) {
#pragma unroll
            for (int c = 0; c < 5; ++c) {
                const int j0 = c * 3;
                f2 acc = conv_begin(wp, j0, bp, c, g[x]);
                conv_step(wp, j0 + 1, g[x + 1], acc);
                conv_step(wp, j0 + 2, g[x + 2], acc);
                ha[c][x] = relu2(acc);
            }
        }
    }

    { f2 wp[38], bp[3]; load_w75(w1, b1, wp, bp); conv5p<14>(ha, hb, wp, bp); }
    { f2 wp[38], bp[3]; load_w75(w2, b2, wp, bp); conv5p<12>(hb, ha, wp, bp); }
    { f2 wp[38], bp[3]; load_w75(w3, b3, wp, bp); conv5p<10>(ha, hb, wp, bp); }
    { f2 wp[38], bp[3]; load_w75(w4, b4, wp, bp); conv5p<8> (hb, ha, wp, bp); }
    { f2 wp[38], bp[3]; load_w75(w5, b5, wp, bp); conv5p<6> (ha, hb, wp, bp); }

    // Layer 6: 5 -> 1, width 4 -> 2, then pair-average.
    {
        f2 wp[8], bp[3];
        load_w15(w6, b6, 1, wp, bp);
        f2 t0 = conv_begin(wp, 0, bp, 0, hb[0][0]);
        f2 t1 = conv_begin(wp, 0, bp, 0, hb[0][1]);
        conv_step(wp, 1, hb[0][1], t0);
        conv_step(wp, 2, hb[0][2], t0);
        conv_step(wp, 1, hb[0][2], t1);
        conv_step(wp, 2, hb[0][3], t1);
#pragma unroll
        for (int ci = 1; ci < 5; ++ci) {
#pragma unroll
            for (int t = 0; t < 3; ++t) {
                conv_step(wp, ci * 3 + t, hb[ci][0 + t], t0);
                conv_step(wp, ci * 3 + t, hb[ci][1 + t], t1);
            }
        }
        t0 = relu2(t0);
        t1 = relu2(t1);
        f2 o = (t0 + t1) * 0.5f;
        zout[(size_t)n0 * BB + lane]       = o.x;
        zout[(size_t)(n0 + 1) * BB + lane] = o.y;
    }
}

// ---------------------------------------------------------------------------
// Final driver gather: out[b, i] = z[driver_idx[i], b]   (out is (B, NDRV))
__global__ __launch_bounds__(256) void gather_out_kernel(
    const float* __restrict__ z, const int* __restrict__ didx,
    float* __restrict__ out)
{
    int i = blockIdx.x * 256 + threadIdx.x;
    if (i >= BB * NDRVN) return;
    int b = i / NDRVN;
    int k = i - b * NDRVN;
    out[i] = z[(size_t)didx[k] * BB + b];
}

// ---------------------------------------------------------------------------
extern "C" void kernel_launch(void* const* d_in, const int* in_sizes, int n_in,
                              void* d_out, int out_size, void* d_ws, size_t ws_size,
                              hipStream_t stream)
{
    const float* x    = (const float*)d_in[0];
    const int*   nidx = (const int*)  d_in[1];
    const int*   didx = (const int*)  d_in[2];
    const float* w[7];
    const float* b[7];
    for (int i = 0; i < 7; ++i) {
        w[i] = (const float*)d_in[3 + 2 * i];
        b[i] = (const float*)d_in[4 + 2 * i];
    }

    // Workspace: two ping-pong z buffers in (N, B) layout, 12.8 MB each.
    float* z0 = (float*)d_ws;
    float* z1 = z0 + (size_t)NB * BB;

    const int tblocks = (NB * BB) / 256;   // 12500 (transpose)
    const int pblocks = NB / 8;            // 6250: 4 waves x 2 nodes

    transpose_kernel<<<tblocks, 256, 0, stream>>>(x, z0);

    pass_kernel<<<pblocks, 256, 0, stream>>>(z0, z1, nidx,
        w[0], b[0], w[1], b[1], w[2], b[2], w[3], b[3],
        w[4], b[4], w[5], b[5], w[6], b[6]);
    pass_kernel<<<pblocks, 256, 0, stream>>>(z1, z0, nidx,
        w[0], b[0], w[1], b[1], w[2], b[2], w[3], b[3],
        w[4], b[4], w[5], b[5], w[6], b[6]);
    pass_kernel<<<pblocks, 256, 0, stream>>>(z0, z1, nidx,
        w[0], b[0], w[1], b[1], w[2], b[2], w[3], b[3],
        w[4], b[4], w[5], b[5], w[6], b[6]);
    pass_kernel<<<pblocks, 256, 0, stream>>>(z1, z0, nidx,
        w[0], b[0], w[1], b[1], w[2], b[2], w[3], b[3],
        w[4], b[4], w[5], b[5], w[6], b[6]);

    gather_out_kernel<<<(BB * NDRVN + 255) / 256, 256, 0, stream>>>(z0, didx, (float*)d_out);
}